// Round 7
// baseline (412.900 us; speedup 1.0000x reference)
//
#include <hip/hip_runtime.h>
#include <math.h>

// ---------------- problem constants ----------------
#define NB 16
#define TT 12
#define H1 47
#define W1D 46
#define H2 46
#define W2D 44

// slot spans (shorts): SLF guard + NB*Ho*Wo*32 + SLB slack
#define SLF 32
#define SPAN1C 1115168   // 32 + 16*47*46*32 + 8192
#define SPAN2C 1044512   // 32 + 16*46*44*32 + 8192

typedef short short8v __attribute__((ext_vector_type(8)));
typedef float floatx4 __attribute__((ext_vector_type(4)));
typedef unsigned int u32x4 __attribute__((ext_vector_type(4)));

__device__ __forceinline__ short f2bf(float x) {
    unsigned u = __float_as_uint(x);
    u = (u + 0x7FFFu + ((u >> 16) & 1u)) >> 16;   // RNE
    return (short)u;
}
__device__ __forceinline__ float bf2f(short s) {
    return __uint_as_float(((unsigned)(unsigned short)s) << 16);
}
__device__ __forceinline__ float hsig(float z) {
    return fminf(fmaxf(0.2f * z + 0.5f, 0.f), 1.f);
}

// ---- plain (non-atomic) cache-bypassing VMEM ops: coalesce + pipeline, ----
// ---- served at the memory-side LLC which is coherent across XCDs.       ----
#define GLOAD16(dst, addr) \
    asm volatile("global_load_dwordx4 %0, %1, off sc0 sc1" : "=v"(dst) : "v"(addr))
#define GSTORE16(addr, val) \
    asm volatile("global_store_dwordx4 %0, %1, off sc0 sc1" :: "v"(addr), "v"(val) : "memory")
#define VMWAIT() do { asm volatile("s_waitcnt vmcnt(0)" ::: "memory"); \
                      __builtin_amdgcn_sched_barrier(0); } while (0)

__device__ __forceinline__ int ldflag(const int* p) {
    int r;
    asm volatile("global_load_dword %0, %1, off sc0 sc1\n\ts_waitcnt vmcnt(0)"
                 : "=v"(r) : "v"(p) : "memory");
    return r;
}

// ---------------------------------------------------------------------------
// Weights -> MFMA B-fragment layout, bf16 (unchanged, verified).
// flat idx = ((c*2+fh)*4+g)*512 + j*32 + ci ; column = g*32+fh*16+j, k = ci
// ---------------------------------------------------------------------------
__global__ __launch_bounds__(256) void transform_w(
    const float* __restrict__ W1s, const float* __restrict__ U1s,
    const float* __restrict__ W2s, const float* __restrict__ U2s,
    short* __restrict__ Bt1, short* __restrict__ Bt2)
{
    int idx = blockIdx.x * 256 + threadIdx.x;       // 0..77823
    int layer2 = idx >= 28672;
    int i = layer2 ? idx - 28672 : idx;
    int ci = i & 31, j = (i >> 5) & 15, g = (i >> 9) & 3, fh = (i >> 11) & 1, c = i >> 12;
    int col = g * 32 + fh * 16 + j;
    float v = 0.f;
    if (!layer2) {
        if (c == 0) {
            if (ci < 18) { int kk = ci / 3, cc = ci - kk * 3; v = W1s[(kk * 3 + cc) * 128 + col]; }
        } else {
            v = U1s[((c - 1) * 32 + ci) * 128 + col];
        }
    } else {
        if (c < 6) v = W2s[(c * 32 + ci) * 128 + col];
        else       v = U2s[((c - 6) * 32 + ci) * 128 + col];
    }
    (layer2 ? Bt2 : Bt1)[i] = f2bf(v);
}

// ---------------------------------------------------------------------------
// L1 x-im2col staging (flag-independent; hoisted before the wait).
// m = r2*48 + x (2 rows x 48 cols), k = kk*3+cc (18 -> pad 32), LDS m*40+k.
// ---------------------------------------------------------------------------
__device__ __forceinline__ void stage_im2col(
    const float* __restrict__ xf, int t, int b, int y0, short* ldsaux, int tid)
{
    const float* xb0 = xf + b * (TT * 48 * 48 * 3) + t * 6912;
    for (int i = tid; i < 3072; i += 128) {
        int m = i >> 5, k = i & 31;
        short v = 0;
        if (k < 18) {
            int kk = k / 3, cc = k - kk * 3;
            int ky = (kk >= 3) ? 1 : 0, kx = kk - ky * 3;
            int r2 = m / 48, xm = m - r2 * 48;
            int ys = y0 + r2 + ky; if (ys > 47) ys = 47;
            int xs = xm + kx;      if (xs > 47) xs = 47;
            v = f2bf(xb0[(ys * 48 + xs) * 3 + cc]);
        }
        ldsaux[m * 40 + k] = v;
    }
}

// ---------------------------------------------------------------------------
// One band step (2 rows x 48 cols). 128 thr = 2 fh waves.
// frag a: row r2=a/3, xbase=(a%3)*16. rec/aux LDS: [3 rows][50 cols] stride 40.
// ---------------------------------------------------------------------------
template<int LAYER>
__device__ __forceinline__ void step_main(
    const short* __restrict__ xin,     // L2: h1(t) slot
    const short* __restrict__ hprev,   // h(t-1) slot
    const short* __restrict__ Bt,
    const float* __restrict__ bias,
    floatx4* cst,
    short* __restrict__ hnext,
    short* __restrict__ pool, int t,
    int b, int ty, short* ldsrec, short* ldsaux, short* ldsH)
{
    constexpr int Ho   = (LAYER == 1) ? H1 : H2;
    constexpr int Wo   = (LAYER == 1) ? W1D : W2D;
    constexpr int NCH  = (LAYER == 1) ? 7 : 12;
    constexpr int REC0 = (LAYER == 1) ? 1 : 6;
    constexpr int HBS  = Ho * Wo * 32;

    const int tid = threadIdx.x;
    const int lane = tid & 63;
    const int fh = tid >> 6;
    const int tx = lane & 15, q = lane >> 4;
    const int y0 = 2 * ty;

    // ---- rec staging: rows y0..y0+2, cols -1..48 (150 pos x 4 x 16B) ----
    u32x4 rv[5]; int rof[5], rok[5];
    {
        const short* hb0 = hprev + b * HBS;
#pragma unroll
        for (int k = 0; k < 5; ++k) {
            rok[k] = 0; rof[k] = 0;
            int i = tid + k * 128;
            if (i < 600) {
                int p = i >> 2, c4 = i & 3;
                int row = p / 50, col = p - row * 50;
                int y = y0 + row, xx = col - 1;
                bool inb = (y < Ho) && ((unsigned)xx < (unsigned)Wo);
                const short* ga = inb ? (hb0 + (y * Wo + xx) * 32 + c4 * 8) : hb0;
                GLOAD16(rv[k], ga);
                rok[k] = inb ? 1 : 2;
                rof[k] = p * 40 + c4 * 8;
            }
        }
    }
    u32x4 av[5]; int aof[5], aok[5];
    if (LAYER == 2) {
        // aux staging: h1(t) rows y0..y0+2 (clamp), cols 0..49 (slack-read OK)
        const short* ib0 = xin + b * (H1 * W1D * 32);
#pragma unroll
        for (int k = 0; k < 5; ++k) {
            aok[k] = 0; aof[k] = 0;
            int i = tid + k * 128;
            if (i < 600) {
                int p = i >> 2, c4 = i & 3;
                int row = p / 50, col = p - row * 50;
                int ys = y0 + row; if (ys > H1 - 1) ys = H1 - 1;
                GLOAD16(av[k], ib0 + (ys * W1D + col) * 32 + c4 * 8);
                aok[k] = 1;
                aof[k] = p * 40 + c4 * 8;
            }
        }
    }
    VMWAIT();
#pragma unroll
    for (int k = 0; k < 5; ++k)
        if (rok[k]) *(u32x4*)&ldsrec[rof[k]] = (rok[k] == 1) ? rv[k] : (u32x4)0;
    if (LAYER == 2) {
#pragma unroll
        for (int k = 0; k < 5; ++k)
            if (aok[k]) *(u32x4*)&ldsaux[aof[k]] = av[k];
    }
    __syncthreads();

    const short* Btl = Bt + fh * 2048 + tx * 32 + q * 8;
    floatx4 acc[6][4] = {};   // [a][gate]

#pragma unroll
    for (int c = 0; c < NCH; ++c) {
        short8v bf4[4], af[6];
#pragma unroll
        for (int g = 0; g < 4; ++g)
            bf4[g] = *(const short8v*)(Btl + c * 4096 + g * 512);

        if (LAYER == 1 && c == 0) {
#pragma unroll
            for (int a = 0; a < 6; ++a)
                af[a] = *(const short8v*)&ldsaux[(a * 16 + tx) * 40 + q * 8];
        } else {
            const bool isaux = (LAYER == 2) && (c < 6);
            int kk = isaux ? c : (c - REC0);
            int ky = (kk >= 3) ? 1 : 0, kx = kk - ky * 3;
            const short* src = isaux ? ldsaux : ldsrec;
#pragma unroll
            for (int a = 0; a < 6; ++a)
                af[a] = *(const short8v*)&src[((a / 3 + ky) * 50 + (a % 3) * 16 + tx + kx) * 40 + q * 8];
        }
#pragma unroll
        for (int a = 0; a < 6; ++a)
#pragma unroll
            for (int g = 0; g < 4; ++g)
                acc[a][g] = __builtin_amdgcn_mfma_f32_16x16x32_bf16(af[a], bf4[g], acc[a][g], 0, 0, 0);
    }

    // ---- fused LSTM epilogue: pixel-in-frag = q*4+r -> x = (a%3)*16+q*4+r ----
    const int f = fh * 16 + tx;
    const float bi = bias[f], bfv = bias[32 + f], bcv = bias[64 + f], bov = bias[96 + f];
    float hv[6][4];
#pragma unroll
    for (int a = 0; a < 6; ++a) {
        floatx4 cold = cst[a];
        floatx4 cnew;
#pragma unroll
        for (int r = 0; r < 4; ++r) {
            float ig = hsig(acc[a][0][r] + bi);
            float fg = hsig(acc[a][1][r] + bfv);
            float gg = fmaxf(acc[a][2][r] + bcv, 0.f);
            float og = hsig(acc[a][3][r] + bov);
            float cn = fg * cold[r] + ig * gg;
            cnew[r] = cn;
            short hb = f2bf(og * fmaxf(cn, 0.f));
            int pos = (a / 3) * 48 + (a % 3) * 16 + q * 4 + r;
            ldsH[pos * 40 + f] = hb;
            hv[a][r] = bf2f(hb);
        }
        cst[a] = cnew;
    }
    __syncthreads();   // ldsH complete (both waves)

    // ---- flush h band via bypass 16B stores (mask y/x) ----
    {
        short* hb_out = hnext + b * HBS;
#pragma unroll
        for (int k = 0; k < 3; ++k) {
            int j = tid + k * 128;                    // 96 pos x 4 chunks
            int pos = j >> 2, c4 = j & 3;
            int pr = pos / 48;
            int y = y0 + pr, xx = pos - pr * 48;
            if (y < Ho && xx < Wo) {
                u32x4 w = *(const u32x4*)&ldsH[pos * 40 + c4 * 8];
                GSTORE16(hb_out + (y * Wo + xx) * 32 + c4 * 8, w);
            }
        }
    }

    if (LAYER == 2) {
        // MaxPool(2,2): the band's 2 rows -> pool row py = ty
        int py = ty;
#pragma unroll
        for (int ac = 0; ac < 3; ++ac) {
#pragma unroll
            for (int rp = 0; rp < 2; ++rp) {
                int px = ac * 8 + q * 2 + rp;
                if (px < 22) {
                    float m = fmaxf(fmaxf(hv[ac][2 * rp],     hv[ac][2 * rp + 1]),
                                    fmaxf(hv[ac + 3][2 * rp], hv[ac + 3][2 * rp + 1]));
                    pool[(size_t)b * 194304 + ((t * 23 + py) * 22 + px) * 32 + f] = f2bf(m);
                }
            }
        }
    }
}

// ---------------------------------------------------------------------------
// Persistent 1-D band pipeline. grid = 752 x 128 thr.
// gid < 384: L1 (b = gid/24, ty = gid%24); else L2 (b, ty2 = 0..22).
// h1/h2: 4-slot rings (slot = t&3, WAR slack 3). prog flags: completed steps.
// Waits (lane = tid, dd relative to t; skip if target < 1):
//  L1: [0] down-L1  >= t   (rec data, row y0+2)
//      [1] up-L1    >= t-2 (WAR: rec reader of my slot)
//      [2] L2(ty-1) >= t-3 (WAR: aux reader)   [3] L2(ty) >= t-3 (WAR)
//  L2: [0] L1(ty)   >= t+1 (aux data) [1] L1(ty+1) >= t+1 (aux data)
//      [2] down-L2  >= t   (rec data)  [3] up-L2  >= t-2 (WAR)
// Rank 2t+layer strictly decreases along every edge -> acyclic.
// 752 blocks, 31.7KB LDS -> 5 blk/CU -> all co-resident -> no deadlock.
// ---------------------------------------------------------------------------
__global__ __launch_bounds__(128, 2) void fused_persistent(
    const float* __restrict__ x,
    short* __restrict__ h1base, short* __restrict__ h2base,
    const short* __restrict__ Bt1, const short* __restrict__ Bt2,
    const float* __restrict__ b1, const float* __restrict__ b2,
    short* __restrict__ pool, int* __restrict__ prog)
{
    __shared__ __align__(16) short ldsrec[6000];
    __shared__ __align__(16) short ldsaux[6000];
    __shared__ __align__(16) short ldsH[3840];

    const int tid = threadIdx.x;
    int gid = blockIdx.x;
    int layer, b, ty;
    if (gid < 384) { layer = 0; b = gid / 24; ty = gid - b * 24; }
    else           { int g2 = gid - 384; layer = 1; b = g2 / 23; ty = g2 - b * 23; }

    // per-lane wait descriptor (constant across steps)
    int fofs = -1, dd = 0;
    if (layer == 0) {
        if (tid == 0 && ty + 1 < 24) { fofs = (b * 24 + ty + 1) * 16; dd = 0;  }
        if (tid == 1 && ty >= 1)     { fofs = (b * 24 + ty - 1) * 16; dd = -2; }
        if (tid == 2 && ty >= 1)     { fofs = 6144 + (b * 23 + ty - 1) * 16; dd = -3; }
        if (tid == 3 && ty < 23)     { fofs = 6144 + (b * 23 + ty) * 16;     dd = -3; }
    } else {
        if (tid == 0)                { fofs = (b * 24 + ty) * 16;     dd = 1; }
        if (tid == 1)                { fofs = (b * 24 + ty + 1) * 16; dd = 1; }
        if (tid == 2 && ty + 1 < 23) { fofs = 6144 + (b * 23 + ty + 1) * 16; dd = 0;  }
        if (tid == 3 && ty >= 1)     { fofs = 6144 + (b * 23 + ty - 1) * 16; dd = -2; }
    }
    int myf = layer ? (6144 + (b * 23 + ty) * 16) : ((b * 24 + ty) * 16);

    floatx4 cst[6];
#pragma unroll
    for (int a = 0; a < 6; ++a) cst[a] = (floatx4)0.f;

    for (int t = 0; t < TT; ++t) {
        // flag-independent staging off the critical chain
        if (layer == 0) stage_im2col(x, t, b, 2 * ty, ldsaux, tid);

        // ---- wait on <=4 flags (one per lane) ----
        if (fofs >= 0) {
            int tg = t + dd;
            if (tg >= 1) {
                const int* pp = prog + fofs;
                while (ldflag(pp) < tg) __builtin_amdgcn_s_sleep(8);
            }
        }
        __syncthreads();

        const short* h1r = h1base + ((t + 3) & 3) * SPAN1C + SLF;   // h1(t-1)
        short*       h1w = h1base + (t & 3) * SPAN1C + SLF;         // h1(t)
        const short* h2r = h2base + ((t + 3) & 3) * SPAN2C + SLF;   // h2(t-1)
        short*       h2w = h2base + (t & 3) * SPAN2C + SLF;         // h2(t)

        if (layer == 0)
            step_main<1>(nullptr, h1r, Bt1, b1, cst, h1w, nullptr, t,
                         b, ty, ldsrec, ldsaux, ldsH);
        else
            step_main<2>(h1w, h2r, Bt2, b2, cst, h2w, pool, t,
                         b, ty, ldsrec, ldsaux, ldsH);

        // drain bypass stores (per wave), block barrier, publish
        asm volatile("s_waitcnt vmcnt(0)" ::: "memory");
        __syncthreads();
        if (tid == 0) {
            int v = t + 1;
            asm volatile("global_store_dword %0, %1, off sc0 sc1"
                         :: "v"(prog + myf), "v"(v) : "memory");
        }
    }
}

// ---------------------------------------------------------------------------
__global__ __launch_bounds__(256) void gemv_kernel(
    const short* __restrict__ p, const float* __restrict__ Wd1, float* __restrict__ d1)
{
    int by = blockIdx.y;                 // batch group: 4*by .. 4*by+3
    int k0 = blockIdx.x * 3036;          // 194304 / 64
    float part[4][10];
#pragma unroll
    for (int bb = 0; bb < 4; bb++)
#pragma unroll
        for (int j = 0; j < 10; j++) part[bb][j] = 0.f;

    for (int k = k0 + threadIdx.x; k < k0 + 3036; k += 256) {
        const float* wr = Wd1 + (size_t)k * 10;
        float wv[10];
#pragma unroll
        for (int j = 0; j < 10; j++) wv[j] = wr[j];
#pragma unroll
        for (int bb = 0; bb < 4; bb++) {
            float m = bf2f(p[(size_t)(by * 4 + bb) * 194304 + k]);
#pragma unroll
            for (int j = 0; j < 10; j++) part[bb][j] = fmaf(m, wv[j], part[bb][j]);
        }
    }
    __shared__ float red[4][10][4];
    int lane = threadIdx.x & 63, wv2 = threadIdx.x >> 6;
#pragma unroll
    for (int bb = 0; bb < 4; bb++)
#pragma unroll
        for (int j = 0; j < 10; j++) {
            float v = part[bb][j];
            for (int off = 32; off > 0; off >>= 1) v += __shfl_down(v, off);
            if (lane == 0) red[bb][j][wv2] = v;
        }
    __syncthreads();
    if (threadIdx.x < 40) {
        int bb = threadIdx.x / 10, j = threadIdx.x % 10;
        float s = red[bb][j][0] + red[bb][j][1] + red[bb][j][2] + red[bb][j][3];
        atomicAdd(&d1[(by * 4 + bb) * 10 + j], s);
    }
}

__global__ void final_dense(const float* __restrict__ d1, const float* __restrict__ bd1,
                            const float* __restrict__ Wd2, const float* __restrict__ bd2,
                            float* __restrict__ out)
{
    int b = threadIdx.x;
    if (b < NB) {
        float s = bd2[0];
#pragma unroll
        for (int j = 0; j < 10; j++) s += (d1[b * 10 + j] + bd1[j]) * Wd2[j];
        out[b] = s;
    }
}

// ---------------------------------------------------------------------------
extern "C" void kernel_launch(void* const* d_in, const int* in_sizes, int n_in,
                              void* d_out, int out_size, void* d_ws, size_t ws_size,
                              hipStream_t stream)
{
    const float* x   = (const float*)d_in[0];
    const float* W1s = (const float*)d_in[1];
    const float* U1s = (const float*)d_in[2];
    const float* b1  = (const float*)d_in[3];
    const float* W2s = (const float*)d_in[4];
    const float* U2s = (const float*)d_in[5];
    const float* b2  = (const float*)d_in[6];
    const float* Wd1 = (const float*)d_in[7];
    const float* bd1 = (const float*)d_in[8];
    const float* Wd2 = (const float*)d_in[9];
    const float* bd2 = (const float*)d_in[10];
    float* out = (float*)d_out;

    short* Bt1 = (short*)d_ws;            // 28672
    short* Bt2 = Bt1 + 28672;             // 49152
    short* p   = Bt2 + 49152;             // 3108864
    short* h1base = p + 3108864;          // 4 slots x SPAN1C
    short* h2base = h1base + 4 * SPAN1C;  // 4 slots x SPAN2C
    float* d1  = (float*)(h2base + 4 * SPAN2C);
    int* prog  = (int*)(d1 + 160);        // 6144 (L1) + 5888 (L2) ints

    // zero only: h1 slot3 (t=-1 state), h2 slot3 + d1 + prog (contiguous)
    hipMemsetAsync(h1base + 3 * SPAN1C, 0, (size_t)SPAN1C * 2, stream);
    hipMemsetAsync(h2base + 3 * SPAN2C, 0,
                   (size_t)SPAN2C * 2 + 160 * 4 + 12288 * 4, stream);

    transform_w<<<304, 256, 0, stream>>>(W1s, U1s, W2s, U2s, Bt1, Bt2);

    // single persistent launch: 1-D band pipeline, flag-based sync
    fused_persistent<<<dim3(752), 128, 0, stream>>>(
        x, h1base, h2base, Bt1, Bt2, b1, b2, p, prog);

    gemv_kernel<<<dim3(64, 4), 256, 0, stream>>>(p, Wd1, d1);
    final_dense<<<1, 64, 0, stream>>>(d1, bd1, Wd2, bd2, out);
}